// Round 5
// baseline (450.774 us; speedup 1.0000x reference)
//
#include <hip/hip_runtime.h>
#include <hip/hip_bf16.h>

#define NB 256
#define IDIM 768
#define NPP 729        // 27*27 patches per image
#define PSTRIDE 768    // padded patch rows per image (12*64)
#define NIMG 64
#define ITERS 50
#define LN 64          // patches per lca block
#define LBLK 12        // lca blocks per image

typedef float f32x4 __attribute__((ext_vector_type(4)));
typedef short bf16x8 __attribute__((ext_vector_type(8)));

__device__ __forceinline__ short f2bf(float x) {
  union { float f; unsigned u; } v; v.f = x;
  unsigned r = v.u + 0x7FFFu + ((v.u >> 16) & 1u);
  return (short)(r >> 16);
}

__device__ __forceinline__ float bf2f(short s) {
  return __uint_as_float((unsigned)(unsigned short)s << 16);
}

__device__ __forceinline__ unsigned cvt_pk_bf16(float lo, float hi) {
  unsigned r;
  asm("v_cvt_pk_bf16_f32 %0, %1, %2" : "=v"(r) : "v"(lo), "v"(hi));
  return r;
}

// ---------------- D -> bf16 ----------------
__global__ __launch_bounds__(256) void k_cvt(const float* __restrict__ D,
                                             short* __restrict__ Dbf) {
  size_t i = (size_t)(blockIdx.x * 256 + threadIdx.x) * 8;
  float4 a = *(const float4*)(D + i);
  float4 b = *(const float4*)(D + i + 4);
  union { uint4 u4; bf16x8 v; } cv;
  cv.u4.x = cvt_pk_bf16(a.x, a.y); cv.u4.y = cvt_pk_bf16(a.z, a.w);
  cv.u4.z = cvt_pk_bf16(b.x, b.y); cv.u4.w = cvt_pk_bf16(b.z, b.w);
  *(bf16x8*)(Dbf + i) = cv.v;
}

// ---------------- per-row sums of Dbf (for affine standardization fold) -----
__global__ __launch_bounds__(256) void k_dsum(const short* __restrict__ Dbf,
                                              float* __restrict__ dsum) {
  int j = threadIdx.x;
  float s = 0.f;
  for (int kc = 0; kc < 96; ++kc) {
    bf16x8 v = *(const bf16x8*)(Dbf + (size_t)j * IDIM + kc * 8);
    #pragma unroll
    for (int i = 0; i < 8; ++i) s += bf2f(v[i]);
  }
  dsum[j] = s;
}

// ---------------- gram = Dbf Dbf^T - I (bf16 out), MFMA ----------------
__global__ __launch_bounds__(256) void k_gram(const short* __restrict__ Dbf,
                                              short* __restrict__ gram) {
  int r0 = blockIdx.x * 16;
  int t = threadIdx.x, w = t >> 6, l = t & 63, lr = l & 15, q = l >> 4;
  f32x4 acc[4];
  #pragma unroll
  for (int c = 0; c < 4; ++c) acc[c] = (f32x4){0.f, 0.f, 0.f, 0.f};
  for (int kc = 0; kc < 24; ++kc) {
    int k = kc * 32 + q * 8;
    bf16x8 a = *(const bf16x8*)(Dbf + (size_t)(r0 + lr) * IDIM + k);
    #pragma unroll
    for (int c = 0; c < 4; ++c) {
      int col = (w * 4 + c) * 16 + lr;
      bf16x8 b = *(const bf16x8*)(Dbf + (size_t)col * IDIM + k);
      acc[c] = __builtin_amdgcn_mfma_f32_16x16x32_bf16(a, b, acc[c], 0, 0, 0);
    }
  }
  #pragma unroll
  for (int c = 0; c < 4; ++c)
    #pragma unroll
    for (int r = 0; r < 4; ++r) {
      int row = r0 + q * 4 + r, col = (w * 4 + c) * 16 + lr;
      gram[row * NB + col] = f2bf(acc[c][r] - (row == col ? 1.f : 0.f));
    }
}

// ---- unfold + b = (p@D^T - mean*dsum)*inv, transposed store ----
__global__ __launch_bounds__(256) void k_patches(const float* __restrict__ img,
                                                 const short* __restrict__ Dbf,
                                                 const float* __restrict__ dsum,
                                                 float* __restrict__ bbufT) {
  __shared__ float strip[3 * 16 * 224];   // 42KB
  __shared__ float s_mean[32], s_inv[32];
  int py = blockIdx.x, im = blockIdx.y;
  int t = threadIdx.x;

  for (int i = t; i < 2688; i += 256) {
    int c = i / 896, rem = i - c * 896, ph = rem / 56, x = rem - ph * 56;
    float4 v = *(const float4*)(img + ((size_t)(im * 3 + c)) * 50176 +
                                (size_t)(py * 8 + ph) * 224 + x * 4);
    *(float4*)(strip + (c * 16 + ph) * 224 + x * 4) = v;
  }
  if (t >= 216 && t < 221) { s_mean[27 + t - 216] = 0.f; s_inv[27 + t - 216] = 0.f; }
  __syncthreads();
  if (t < 216) {
    int p = t >> 3, s = t & 7;
    float sum = 0.f, ss = 0.f;
    for (int c = 0; c < 3; ++c)
      #pragma unroll
      for (int ph = 0; ph < 16; ++ph) {
        const float* rw = strip + (c * 16 + ph) * 224 + p * 8 + s * 2;
        float v0 = rw[0], v1 = rw[1];
        sum += v0 + v1; ss += v0 * v0 + v1 * v1;
      }
    #pragma unroll
    for (int d = 1; d < 8; d <<= 1) { sum += __shfl_xor(sum, d); ss += __shfl_xor(ss, d); }
    if (s == 0) {
      float mean = sum * (1.f / 768.f);
      float var = (ss - sum * mean) * (1.f / 767.f);
      float sd = sqrtf(fmaxf(var, 0.f));
      s_mean[p] = mean; s_inv[p] = 1.f / (sd + 1e-8f);
    }
  }
  __syncthreads();

  int w = t >> 6, l = t & 63, lr = l & 15, q = l >> 4;
  f32x4 acc[2][4];
  #pragma unroll
  for (int mi = 0; mi < 2; ++mi)
    #pragma unroll
    for (int c = 0; c < 4; ++c) acc[mi][c] = (f32x4){0.f, 0.f, 0.f, 0.f};

  for (int kc = 0; kc < 24; ++kc) {
    int k = kc * 32 + q * 8;
    int c = k >> 8, ph = (k >> 4) & 15, pw0 = k & 15;
    const float* rb = strip + (c * 16 + ph) * 224 + pw0;
    bf16x8 af[2];
    #pragma unroll
    for (int mi = 0; mi < 2; ++mi) {
      int patch = mi * 16 + lr;
      int px = patch < 27 ? patch : 26;        // clamp keeps LDS reads in-bounds
      const float* sp = rb + px * 8;
      float4 v0 = *(const float4*)(sp);
      float4 v1 = *(const float4*)(sp + 4);
      union { uint4 u4; bf16x8 v; } cv;
      cv.u4.x = cvt_pk_bf16(v0.x, v0.y);
      cv.u4.y = cvt_pk_bf16(v0.z, v0.w);
      cv.u4.z = cvt_pk_bf16(v1.x, v1.y);
      cv.u4.w = cvt_pk_bf16(v1.z, v1.w);
      af[mi] = cv.v;
    }
    bf16x8 bfr[4];
    #pragma unroll
    for (int c4 = 0; c4 < 4; ++c4) {
      int col = (w * 4 + c4) * 16 + lr;
      bfr[c4] = *(const bf16x8*)(Dbf + (size_t)col * IDIM + k);
    }
    #pragma unroll
    for (int mi = 0; mi < 2; ++mi)
      #pragma unroll
      for (int c4 = 0; c4 < 4; ++c4)
        acc[mi][c4] = __builtin_amdgcn_mfma_f32_16x16x32_bf16(af[mi], bfr[c4], acc[mi][c4], 0, 0, 0);
  }

  int prow0 = py * 27;
  #pragma unroll
  for (int mi = 0; mi < 2; ++mi)
    #pragma unroll
    for (int c4 = 0; c4 < 4; ++c4) {
      int col = (w * 4 + c4) * 16 + lr;
      float dsv = dsum[col];
      size_t base = ((size_t)(im * NB + col)) * PSTRIDE + prow0;
      #pragma unroll
      for (int r = 0; r < 4; ++r) {
        int patch = mi * 16 + q * 4 + r;
        if (patch < 27) {
          float bv = (acc[mi][c4][r] - s_mean[patch] * dsv) * s_inv[patch];
          bbufT[base + patch] = bv;
        }
      }
    }
}

// ---- 50 LCA iterations: 4M x 2N wave tiling, gram+b+u in regs, a in LDS ----
__global__ __launch_bounds__(512, 2) void k_lca(const float* __restrict__ bbufT,
                                                const short* __restrict__ gram,
                                                float* __restrict__ partial) {
  __shared__ char albuf[2][LN * 512];   // 64KB: double-buffered a (bf16, swizzled)
  int blk = blockIdx.x, im = blockIdx.y;
  int t = threadIdx.x, w = t >> 6, l = t & 63, lr = l & 15, q = l >> 4;
  int wm = w >> 1, wn = w & 1;
  int p0 = blk * LN;
  int basew = wm * 64;                  // wave owns bases [basew, basew+64)
  int pw = wn * 32;                     // wave owns patches [pw, pw+32)

  // gram A-fragments, loop-invariant: rows basew+mi*16+lr, k-slice kc*32+q*8
  bf16x8 gA[4][8];
  #pragma unroll
  for (int mi = 0; mi < 4; ++mi)
    #pragma unroll
    for (int kc = 0; kc < 8; ++kc)
      gA[mi][kc] = *(const bf16x8*)(gram + (size_t)(basew + mi * 16 + lr) * NB + kc * 32 + q * 8);

  // b (pre-scaled by dt/tau=0.01) packed in regs; u_1 = 0.01*b
  float u[4][2][4];
  int2 bpk[4][2];
  #pragma unroll
  for (int mi = 0; mi < 4; ++mi) {
    int basis0 = basew + mi * 16 + q * 4;
    #pragma unroll
    for (int nt = 0; nt < 2; ++nt) {
      int patch = pw + nt * 16 + lr;
      size_t ga = ((size_t)(im * NB + basis0)) * PSTRIDE + p0 + patch;
      float b0 = bbufT[ga] * 0.01f;
      float b1 = bbufT[ga + PSTRIDE] * 0.01f;
      float b2 = bbufT[ga + 2 * PSTRIDE] * 0.01f;
      float b3 = bbufT[ga + 3 * PSTRIDE] * 0.01f;
      int2 pk = make_int2((int)cvt_pk_bf16(b0, b1), (int)cvt_pk_bf16(b2, b3));
      bpk[mi][nt] = pk;
      u[mi][nt][0] = __uint_as_float((unsigned)pk.x << 16);
      u[mi][nt][1] = __uint_as_float((unsigned)pk.x & 0xffff0000u);
      u[mi][nt][2] = __uint_as_float((unsigned)pk.y << 16);
      u[mi][nt][3] = __uint_as_float((unsigned)pk.y & 0xffff0000u);
    }
  }

  for (int it = 0; it < ITERS - 1; ++it) {
    char* abuf = albuf[it & 1];
    // phase 1: a = softshrink(u) -> swizzled LDS (one b64 store per tile)
    #pragma unroll
    for (int mi = 0; mi < 4; ++mi)
      #pragma unroll
      for (int nt = 0; nt < 2; ++nt) {
        int patch = pw + nt * 16 + lr;
        float a0 = u[mi][nt][0] - __builtin_amdgcn_fmed3f(u[mi][nt][0], -0.5f, 0.5f);
        float a1 = u[mi][nt][1] - __builtin_amdgcn_fmed3f(u[mi][nt][1], -0.5f, 0.5f);
        float a2 = u[mi][nt][2] - __builtin_amdgcn_fmed3f(u[mi][nt][2], -0.5f, 0.5f);
        float a3 = u[mi][nt][3] - __builtin_amdgcn_fmed3f(u[mi][nt][3], -0.5f, 0.5f);
        int byte = (patch * 512 + (basew + mi * 16 + q * 4) * 2) ^ ((patch & 7) << 4);
        *(int2*)(abuf + byte) = make_int2((int)cvt_pk_bf16(a0, a1), (int)cvt_pk_bf16(a2, a3));
      }
    __syncthreads();

    // phase 2: acc = gram @ a^T  (A=gram regs, B=a from LDS)
    f32x4 acc[4][2];
    #pragma unroll
    for (int mi = 0; mi < 4; ++mi)
      #pragma unroll
      for (int nt = 0; nt < 2; ++nt) acc[mi][nt] = (f32x4){0.f, 0.f, 0.f, 0.f};
    #pragma unroll
    for (int kc = 0; kc < 8; ++kc) {
      bf16x8 ab[2];
      #pragma unroll
      for (int nt = 0; nt < 2; ++nt) {
        int patch = pw + nt * 16 + lr;
        int byte = (patch * 512 + (kc * 32 + q * 8) * 2) ^ ((patch & 7) << 4);
        ab[nt] = *(const bf16x8*)(abuf + byte);
      }
      #pragma unroll
      for (int mi = 0; mi < 4; ++mi)
        #pragma unroll
        for (int nt = 0; nt < 2; ++nt)
          acc[mi][nt] = __builtin_amdgcn_mfma_f32_16x16x32_bf16(gA[mi][kc], ab[nt], acc[mi][nt], 0, 0, 0);
    }
    // no second barrier: next iter writes the other LDS buffer

    // phase 3: u = 0.99u + 0.01b - 0.01acc
    #pragma unroll
    for (int mi = 0; mi < 4; ++mi)
      #pragma unroll
      for (int nt = 0; nt < 2; ++nt) {
        int2 pk = bpk[mi][nt];
        float b0 = __uint_as_float((unsigned)pk.x << 16);
        float b1 = __uint_as_float((unsigned)pk.x & 0xffff0000u);
        float b2 = __uint_as_float((unsigned)pk.y << 16);
        float b3 = __uint_as_float((unsigned)pk.y & 0xffff0000u);
        u[mi][nt][0] = fmaf(0.99f, u[mi][nt][0], fmaf(-0.01f, acc[mi][nt][0], b0));
        u[mi][nt][1] = fmaf(0.99f, u[mi][nt][1], fmaf(-0.01f, acc[mi][nt][1], b1));
        u[mi][nt][2] = fmaf(0.99f, u[mi][nt][2], fmaf(-0.01f, acc[mi][nt][2], b2));
        u[mi][nt][3] = fmaf(0.99f, u[mi][nt][3], fmaf(-0.01f, acc[mi][nt][3], b3));
      }
  }

  // codes = softshrink(u); per-wave masked max over its 32 patches (reduce lr)
  float mred[4][4];
  #pragma unroll
  for (int mi = 0; mi < 4; ++mi)
    #pragma unroll
    for (int r = 0; r < 4; ++r) {
      float m = -3.402823466e38f;
      #pragma unroll
      for (int nt = 0; nt < 2; ++nt) {
        int patch = p0 + pw + nt * 16 + lr;
        float uu = u[mi][nt][r];
        float a = uu - __builtin_amdgcn_fmed3f(uu, -0.5f, 0.5f);
        if (patch < NPP) m = fmaxf(m, a);
      }
      m = fmaxf(m, __shfl_xor(m, 1));
      m = fmaxf(m, __shfl_xor(m, 2));
      m = fmaxf(m, __shfl_xor(m, 4));
      m = fmaxf(m, __shfl_xor(m, 8));
      mred[mi][r] = m;
    }

  // combine the two patch-half waves through LDS, then one write per basis
  float* xch = (float*)albuf;
  __syncthreads();
  if (wn == 1 && lr == 0) {
    #pragma unroll
    for (int mi = 0; mi < 4; ++mi)
      #pragma unroll
      for (int r = 0; r < 4; ++r)
        xch[basew + mi * 16 + q * 4 + r] = mred[mi][r];
  }
  __syncthreads();
  if (wn == 0 && lr == 0) {
    #pragma unroll
    for (int mi = 0; mi < 4; ++mi)
      #pragma unroll
      for (int r = 0; r < 4; ++r) {
        int basis = basew + mi * 16 + q * 4 + r;
        float m = fmaxf(mred[mi][r], xch[basis]);
        partial[(size_t)(im * LBLK + blk) * NB + basis] = m;
      }
  }
}

// ---------------- reduce 12 partials per image ----------------
__global__ __launch_bounds__(256) void k_pool(const float* __restrict__ partial,
                                              float* __restrict__ out) {
  int im = blockIdx.x, n = threadIdx.x;
  float m = partial[(size_t)(im * LBLK) * NB + n];
  for (int b = 1; b < LBLK; ++b)
    m = fmaxf(m, partial[(size_t)(im * LBLK + b) * NB + n]);
  out[im * NB + n] = m;
}

extern "C" void kernel_launch(void* const* d_in, const int* in_sizes, int n_in,
                              void* d_out, int out_size, void* d_ws, size_t ws_size,
                              hipStream_t stream) {
  const float* img = (const float*)d_in[0];
  const float* D   = (const float*)d_in[1];

  char* ws = (char*)d_ws;
  short* gram    = (short*)(ws);                    // 131072
  short* Dbf     = (short*)(ws + 131072);           // 393216
  float* dsum    = (float*)(ws + 524288);           // 1024 (pad to 4096)
  float* bbufT   = (float*)(ws + 528384);           // 64*256*768*4 = 50331648
  float* partial = (float*)(ws + 50860032);         // 64*12*256*4 = 786432
  float* out = (float*)d_out;

  hipLaunchKernelGGL(k_cvt, dim3(96), dim3(256), 0, stream, D, Dbf);
  hipLaunchKernelGGL(k_dsum, dim3(1), dim3(256), 0, stream, Dbf, dsum);
  hipLaunchKernelGGL(k_gram, dim3(16), dim3(256), 0, stream, Dbf, gram);
  hipLaunchKernelGGL(k_patches, dim3(27, NIMG), dim3(256), 0, stream, img, Dbf, dsum, bbufT);
  hipLaunchKernelGGL(k_lca, dim3(LBLK, NIMG), dim3(512), 0, stream, bbufT, gram, partial);
  hipLaunchKernelGGL(k_pool, dim3(NIMG), dim3(256), 0, stream, partial, out);
}

// Round 7
// 431.991 us; speedup vs baseline: 1.0435x; 1.0435x over previous
//
#include <hip/hip_runtime.h>
#include <hip/hip_bf16.h>

#define NB 256
#define IDIM 768
#define NPP 729        // 27*27 patches per image
#define PSTRIDE 768    // padded patch rows per image (24*32)
#define NIMG 64
#define ITERS 50
#define LN 32          // patches per lca block
#define LBLK 24        // lca blocks per image

typedef float f32x4 __attribute__((ext_vector_type(4)));
typedef short bf16x8 __attribute__((ext_vector_type(8)));

__device__ __forceinline__ short f2bf(float x) {
  union { float f; unsigned u; } v; v.f = x;
  unsigned r = v.u + 0x7FFFu + ((v.u >> 16) & 1u);
  return (short)(r >> 16);
}

__device__ __forceinline__ float bf2f(short s) {
  return __uint_as_float((unsigned)(unsigned short)s << 16);
}

__device__ __forceinline__ unsigned cvt_pk_bf16(float lo, float hi) {
  unsigned r;
  asm("v_cvt_pk_bf16_f32 %0, %1, %2" : "=v"(r) : "v"(lo), "v"(hi));
  return r;
}

// ---------------- D -> bf16 ----------------
__global__ __launch_bounds__(256) void k_cvt(const float* __restrict__ D,
                                             short* __restrict__ Dbf) {
  size_t i = (size_t)(blockIdx.x * 256 + threadIdx.x) * 8;
  float4 a = *(const float4*)(D + i);
  float4 b = *(const float4*)(D + i + 4);
  union { uint4 u4; bf16x8 v; } cv;
  cv.u4.x = cvt_pk_bf16(a.x, a.y); cv.u4.y = cvt_pk_bf16(a.z, a.w);
  cv.u4.z = cvt_pk_bf16(b.x, b.y); cv.u4.w = cvt_pk_bf16(b.z, b.w);
  *(bf16x8*)(Dbf + i) = cv.v;
}

// ---------------- per-row sums of Dbf (for affine standardization fold) -----
__global__ __launch_bounds__(256) void k_dsum(const short* __restrict__ Dbf,
                                              float* __restrict__ dsum) {
  int j = threadIdx.x;
  float s = 0.f;
  for (int kc = 0; kc < 96; ++kc) {
    bf16x8 v = *(const bf16x8*)(Dbf + (size_t)j * IDIM + kc * 8);
    #pragma unroll
    for (int i = 0; i < 8; ++i) s += bf2f(v[i]);
  }
  dsum[j] = s;
}

// ---------------- gram = Dbf Dbf^T - I (bf16 out), MFMA ----------------
__global__ __launch_bounds__(256) void k_gram(const short* __restrict__ Dbf,
                                              short* __restrict__ gram) {
  int r0 = blockIdx.x * 16;
  int t = threadIdx.x, w = t >> 6, l = t & 63, lr = l & 15, q = l >> 4;
  f32x4 acc[4];
  #pragma unroll
  for (int c = 0; c < 4; ++c) acc[c] = (f32x4){0.f, 0.f, 0.f, 0.f};
  for (int kc = 0; kc < 24; ++kc) {
    int k = kc * 32 + q * 8;
    bf16x8 a = *(const bf16x8*)(Dbf + (size_t)(r0 + lr) * IDIM + k);
    #pragma unroll
    for (int c = 0; c < 4; ++c) {
      int col = (w * 4 + c) * 16 + lr;
      bf16x8 b = *(const bf16x8*)(Dbf + (size_t)col * IDIM + k);
      acc[c] = __builtin_amdgcn_mfma_f32_16x16x32_bf16(a, b, acc[c], 0, 0, 0);
    }
  }
  #pragma unroll
  for (int c = 0; c < 4; ++c)
    #pragma unroll
    for (int r = 0; r < 4; ++r) {
      int row = r0 + q * 4 + r, col = (w * 4 + c) * 16 + lr;
      gram[row * NB + col] = f2bf(acc[c][r] - (row == col ? 1.f : 0.f));
    }
}

// ---- unfold + b = (p@D^T - mean*dsum)*inv, transposed store ----
__global__ __launch_bounds__(256) void k_patches(const float* __restrict__ img,
                                                 const short* __restrict__ Dbf,
                                                 const float* __restrict__ dsum,
                                                 float* __restrict__ bbufT) {
  __shared__ float strip[3 * 16 * 224];   // 42KB
  __shared__ float s_mean[32], s_inv[32];
  int py = blockIdx.x, im = blockIdx.y;
  int t = threadIdx.x;

  for (int i = t; i < 2688; i += 256) {
    int c = i / 896, rem = i - c * 896, ph = rem / 56, x = rem - ph * 56;
    float4 v = *(const float4*)(img + ((size_t)(im * 3 + c)) * 50176 +
                                (size_t)(py * 8 + ph) * 224 + x * 4);
    *(float4*)(strip + (c * 16 + ph) * 224 + x * 4) = v;
  }
  if (t >= 216 && t < 221) { s_mean[27 + t - 216] = 0.f; s_inv[27 + t - 216] = 0.f; }
  __syncthreads();
  if (t < 216) {
    int p = t >> 3, s = t & 7;
    float sum = 0.f, ss = 0.f;
    for (int c = 0; c < 3; ++c)
      #pragma unroll
      for (int ph = 0; ph < 16; ++ph) {
        const float* rw = strip + (c * 16 + ph) * 224 + p * 8 + s * 2;
        float v0 = rw[0], v1 = rw[1];
        sum += v0 + v1; ss += v0 * v0 + v1 * v1;
      }
    #pragma unroll
    for (int d = 1; d < 8; d <<= 1) { sum += __shfl_xor(sum, d); ss += __shfl_xor(ss, d); }
    if (s == 0) {
      float mean = sum * (1.f / 768.f);
      float var = (ss - sum * mean) * (1.f / 767.f);
      float sd = sqrtf(fmaxf(var, 0.f));
      s_mean[p] = mean; s_inv[p] = 1.f / (sd + 1e-8f);
    }
  }
  __syncthreads();

  int w = t >> 6, l = t & 63, lr = l & 15, q = l >> 4;
  f32x4 acc[2][4];
  #pragma unroll
  for (int mi = 0; mi < 2; ++mi)
    #pragma unroll
    for (int c = 0; c < 4; ++c) acc[mi][c] = (f32x4){0.f, 0.f, 0.f, 0.f};

  for (int kc = 0; kc < 24; ++kc) {
    int k = kc * 32 + q * 8;
    int c = k >> 8, ph = (k >> 4) & 15, pw0 = k & 15;
    const float* rb = strip + (c * 16 + ph) * 224 + pw0;
    bf16x8 af[2];
    #pragma unroll
    for (int mi = 0; mi < 2; ++mi) {
      int patch = mi * 16 + lr;
      int px = patch < 27 ? patch : 26;        // clamp keeps LDS reads in-bounds
      const float* sp = rb + px * 8;
      float4 v0 = *(const float4*)(sp);
      float4 v1 = *(const float4*)(sp + 4);
      union { uint4 u4; bf16x8 v; } cv;
      cv.u4.x = cvt_pk_bf16(v0.x, v0.y);
      cv.u4.y = cvt_pk_bf16(v0.z, v0.w);
      cv.u4.z = cvt_pk_bf16(v1.x, v1.y);
      cv.u4.w = cvt_pk_bf16(v1.z, v1.w);
      af[mi] = cv.v;
    }
    bf16x8 bfr[4];
    #pragma unroll
    for (int c4 = 0; c4 < 4; ++c4) {
      int col = (w * 4 + c4) * 16 + lr;
      bfr[c4] = *(const bf16x8*)(Dbf + (size_t)col * IDIM + k);
    }
    #pragma unroll
    for (int mi = 0; mi < 2; ++mi)
      #pragma unroll
      for (int c4 = 0; c4 < 4; ++c4)
        acc[mi][c4] = __builtin_amdgcn_mfma_f32_16x16x32_bf16(af[mi], bfr[c4], acc[mi][c4], 0, 0, 0);
  }

  int prow0 = py * 27;
  #pragma unroll
  for (int mi = 0; mi < 2; ++mi)
    #pragma unroll
    for (int c4 = 0; c4 < 4; ++c4) {
      int col = (w * 4 + c4) * 16 + lr;
      float dsv = dsum[col];
      size_t base = ((size_t)(im * NB + col)) * PSTRIDE + prow0;
      #pragma unroll
      for (int r = 0; r < 4; ++r) {
        int patch = mi * 16 + q * 4 + r;
        if (patch < 27) {
          float bv = (acc[mi][c4][r] - s_mean[patch] * dsv) * s_inv[patch];
          bbufT[base + patch] = bv;
        }
      }
    }
}

// ---- 50 LCA iterations: 4-wave blocks (32 patches), wave tile 64Mx32N ------
// Two independent blocks per CU => anti-phase VALU/MFMA overlap.
__global__ __launch_bounds__(256, 2) void k_lca(const float* __restrict__ bbufT,
                                                const short* __restrict__ gram,
                                                float* __restrict__ partial) {
  __shared__ char albuf[2][LN * 512];   // 32KB: double-buffered a (bf16, swizzled)
  int blk = blockIdx.x, im = blockIdx.y;
  int t = threadIdx.x, w = t >> 6, l = t & 63, lr = l & 15, q = l >> 4;
  int p0 = blk * LN;
  int basew = w * 64;                   // wave owns bases [basew, basew+64)

  // gram A-fragments, loop-invariant: rows basew+mi*16+lr, k-slice kc*32+q*8
  bf16x8 gA[4][8];
  #pragma unroll
  for (int mi = 0; mi < 4; ++mi)
    #pragma unroll
    for (int kc = 0; kc < 8; ++kc)
      gA[mi][kc] = *(const bf16x8*)(gram + (size_t)(basew + mi * 16 + lr) * NB + kc * 32 + q * 8);

  // b (pre-scaled by dt/tau=0.01) packed in regs; u_1 = 0.01*b
  float u[4][2][4];
  int2 bpk[4][2];
  #pragma unroll
  for (int mi = 0; mi < 4; ++mi) {
    int basis0 = basew + mi * 16 + q * 4;
    #pragma unroll
    for (int nt = 0; nt < 2; ++nt) {
      int patch = nt * 16 + lr;
      size_t ga = ((size_t)(im * NB + basis0)) * PSTRIDE + p0 + patch;
      float b0 = bbufT[ga] * 0.01f;
      float b1 = bbufT[ga + PSTRIDE] * 0.01f;
      float b2 = bbufT[ga + 2 * PSTRIDE] * 0.01f;
      float b3 = bbufT[ga + 3 * PSTRIDE] * 0.01f;
      int2 pk = make_int2((int)cvt_pk_bf16(b0, b1), (int)cvt_pk_bf16(b2, b3));
      bpk[mi][nt] = pk;
      u[mi][nt][0] = __uint_as_float((unsigned)pk.x << 16);
      u[mi][nt][1] = __uint_as_float((unsigned)pk.x & 0xffff0000u);
      u[mi][nt][2] = __uint_as_float((unsigned)pk.y << 16);
      u[mi][nt][3] = __uint_as_float((unsigned)pk.y & 0xffff0000u);
    }
  }

  for (int it = 0; it < ITERS - 1; ++it) {
    char* abuf = albuf[it & 1];
    // phase 1: a = softshrink(u) -> swizzled LDS (one b64 store per tile)
    #pragma unroll
    for (int mi = 0; mi < 4; ++mi)
      #pragma unroll
      for (int nt = 0; nt < 2; ++nt) {
        int patch = nt * 16 + lr;
        float a0 = u[mi][nt][0] - __builtin_amdgcn_fmed3f(u[mi][nt][0], -0.5f, 0.5f);
        float a1 = u[mi][nt][1] - __builtin_amdgcn_fmed3f(u[mi][nt][1], -0.5f, 0.5f);
        float a2 = u[mi][nt][2] - __builtin_amdgcn_fmed3f(u[mi][nt][2], -0.5f, 0.5f);
        float a3 = u[mi][nt][3] - __builtin_amdgcn_fmed3f(u[mi][nt][3], -0.5f, 0.5f);
        int byte = (patch * 512 + (basew + mi * 16 + q * 4) * 2) ^ ((patch & 7) << 4);
        *(int2*)(abuf + byte) = make_int2((int)cvt_pk_bf16(a0, a1), (int)cvt_pk_bf16(a2, a3));
      }
    __syncthreads();

    // phase 2: acc = gram @ a^T  (A=gram regs, B=a from LDS)
    f32x4 acc[4][2];
    #pragma unroll
    for (int mi = 0; mi < 4; ++mi)
      #pragma unroll
      for (int nt = 0; nt < 2; ++nt) acc[mi][nt] = (f32x4){0.f, 0.f, 0.f, 0.f};
    #pragma unroll
    for (int kc = 0; kc < 8; ++kc) {
      bf16x8 ab[2];
      #pragma unroll
      for (int nt = 0; nt < 2; ++nt) {
        int patch = nt * 16 + lr;
        int byte = (patch * 512 + (kc * 32 + q * 8) * 2) ^ ((patch & 7) << 4);
        ab[nt] = *(const bf16x8*)(abuf + byte);
      }
      #pragma unroll
      for (int mi = 0; mi < 4; ++mi)
        #pragma unroll
        for (int nt = 0; nt < 2; ++nt)
          acc[mi][nt] = __builtin_amdgcn_mfma_f32_16x16x32_bf16(gA[mi][kc], ab[nt], acc[mi][nt], 0, 0, 0);
    }
    // no second barrier: next iter writes the other LDS buffer

    // phase 3: u = 0.99u + 0.01b - 0.01acc
    #pragma unroll
    for (int mi = 0; mi < 4; ++mi)
      #pragma unroll
      for (int nt = 0; nt < 2; ++nt) {
        int2 pk = bpk[mi][nt];
        float b0 = __uint_as_float((unsigned)pk.x << 16);
        float b1 = __uint_as_float((unsigned)pk.x & 0xffff0000u);
        float b2 = __uint_as_float((unsigned)pk.y << 16);
        float b3 = __uint_as_float((unsigned)pk.y & 0xffff0000u);
        u[mi][nt][0] = fmaf(0.99f, u[mi][nt][0], fmaf(-0.01f, acc[mi][nt][0], b0));
        u[mi][nt][1] = fmaf(0.99f, u[mi][nt][1], fmaf(-0.01f, acc[mi][nt][1], b1));
        u[mi][nt][2] = fmaf(0.99f, u[mi][nt][2], fmaf(-0.01f, acc[mi][nt][2], b2));
        u[mi][nt][3] = fmaf(0.99f, u[mi][nt][3], fmaf(-0.01f, acc[mi][nt][3], b3));
      }
  }

  // codes = softshrink(u); wave-local masked max over the block's 32 patches
  #pragma unroll
  for (int mi = 0; mi < 4; ++mi)
    #pragma unroll
    for (int r = 0; r < 4; ++r) {
      float m = -3.402823466e38f;
      #pragma unroll
      for (int nt = 0; nt < 2; ++nt) {
        int patch = p0 + nt * 16 + lr;
        float uu = u[mi][nt][r];
        float a = uu - __builtin_amdgcn_fmed3f(uu, -0.5f, 0.5f);
        if (patch < NPP) m = fmaxf(m, a);
      }
      m = fmaxf(m, __shfl_xor(m, 1));
      m = fmaxf(m, __shfl_xor(m, 2));
      m = fmaxf(m, __shfl_xor(m, 4));
      m = fmaxf(m, __shfl_xor(m, 8));
      if (lr == 0)
        partial[(size_t)(im * LBLK + blk) * NB + basew + mi * 16 + q * 4 + r] = m;
    }
}

// ---------------- reduce 24 partials per image ----------------
__global__ __launch_bounds__(256) void k_pool(const float* __restrict__ partial,
                                              float* __restrict__ out) {
  int im = blockIdx.x, n = threadIdx.x;
  float m = partial[(size_t)(im * LBLK) * NB + n];
  for (int b = 1; b < LBLK; ++b)
    m = fmaxf(m, partial[(size_t)(im * LBLK + b) * NB + n]);
  out[im * NB + n] = m;
}

extern "C" void kernel_launch(void* const* d_in, const int* in_sizes, int n_in,
                              void* d_out, int out_size, void* d_ws, size_t ws_size,
                              hipStream_t stream) {
  const float* img = (const float*)d_in[0];
  const float* D   = (const float*)d_in[1];

  char* ws = (char*)d_ws;
  short* gram    = (short*)(ws);                    // 131072
  short* Dbf     = (short*)(ws + 131072);           // 393216
  float* dsum    = (float*)(ws + 524288);           // 1024 (pad to 4096)
  float* bbufT   = (float*)(ws + 528384);           // 64*256*768*4 = 50331648
  float* partial = (float*)(ws + 50860032);         // 64*24*256*4 = 1572864
  float* out = (float*)d_out;

  hipLaunchKernelGGL(k_cvt, dim3(96), dim3(256), 0, stream, D, Dbf);
  hipLaunchKernelGGL(k_dsum, dim3(1), dim3(256), 0, stream, Dbf, dsum);
  hipLaunchKernelGGL(k_gram, dim3(16), dim3(256), 0, stream, Dbf, gram);
  hipLaunchKernelGGL(k_patches, dim3(27, NIMG), dim3(256), 0, stream, img, Dbf, dsum, bbufT);
  hipLaunchKernelGGL(k_lca, dim3(LBLK, NIMG), dim3(256), 0, stream, bbufT, gram, partial);
  hipLaunchKernelGGL(k_pool, dim3(NIMG), dim3(256), 0, stream, partial, out);
}